// Round 4
// baseline (940.657 us; speedup 1.0000x reference)
//
#include <hip/hip_runtime.h>
#include <hip/hip_bf16.h>
#include <math.h>

#define N_USERS 100000
#define N_ITEMS 50000
#define N_NODES 150000
#define N_EDGES 1000000
#define SCAN_BLK 256
#define N_SCAN_BLOCKS ((N_NODES + SCAN_BLK - 1) / SCAN_BLK)  // 586

// ---------------- Phase 1: per-edge softmax -> deg atomics + in-degree histogram ----------------
__global__ void dg_deg(const int* __restrict__ ei, const float* __restrict__ intents,
                       float* __restrict__ deg, int* __restrict__ counts) {
    int e = blockIdx.x * blockDim.x + threadIdx.x;
    if (e >= N_EDGES) return;
    float v0 = intents[0 * N_EDGES + e];
    float v1 = intents[1 * N_EDGES + e];
    float v2 = intents[2 * N_EDGES + e];
    float v3 = intents[3 * N_EDGES + e];
    float m  = fmaxf(fmaxf(v0, v1), fmaxf(v2, v3));
    float e0 = __expf(v0 - m), e1 = __expf(v1 - m), e2 = __expf(v2 - m), e3 = __expf(v3 - m);
    float inv = 1.0f / (e0 + e1 + e2 + e3);
    float w0 = e0 * inv, w1 = e1 * inv, w2 = e2 * inv, w3 = e3 * inv;
    int r = ei[e];
    int c = ei[N_EDGES + e];
    atomicAdd(&deg[r * 4 + 0], w0); atomicAdd(&deg[r * 4 + 1], w1);
    atomicAdd(&deg[r * 4 + 2], w2); atomicAdd(&deg[r * 4 + 3], w3);
    atomicAdd(&deg[c * 4 + 0], w0); atomicAdd(&deg[c * 4 + 1], w1);
    atomicAdd(&deg[c * 4 + 2], w2); atomicAdd(&deg[c * 4 + 3], w3);
    atomicAdd(&counts[c], 1);
}

// ---------------- Phase 2: deg -> dis (in place) ----------------
__global__ void dg_dis(float* __restrict__ deg) {
    int i = blockIdx.x * blockDim.x + threadIdx.x;
    if (i >= N_NODES * 4) return;
    float d = deg[i];
    deg[i] = (d > 0.f) ? rsqrtf(fmaxf(d, 1e-12f)) : 0.f;
}

// ---------------- Phase 3: hierarchical exclusive scan of counts -> offsets ----------------
__global__ void dg_scan1(const int* __restrict__ counts, int* __restrict__ offsets,
                         int* __restrict__ partials) {
    __shared__ int s[SCAN_BLK];
    int t = threadIdx.x;
    int i = blockIdx.x * SCAN_BLK + t;
    int v = (i < N_NODES) ? counts[i] : 0;
    s[t] = v;
    __syncthreads();
    for (int off = 1; off < SCAN_BLK; off <<= 1) {
        int a = (t >= off) ? s[t - off] : 0;
        __syncthreads();
        s[t] += a;
        __syncthreads();
    }
    int incl = s[t];
    if (i < N_NODES) offsets[i] = incl - v;          // exclusive within block
    if (t == SCAN_BLK - 1) partials[blockIdx.x] = incl;  // block total
}

__global__ void dg_scan2(int* __restrict__ partials) {
    __shared__ int s[1024];
    int t = threadIdx.x;
    int v = (t < N_SCAN_BLOCKS) ? partials[t] : 0;
    s[t] = v;
    __syncthreads();
    for (int off = 1; off < 1024; off <<= 1) {
        int a = (t >= off) ? s[t - off] : 0;
        __syncthreads();
        s[t] += a;
        __syncthreads();
    }
    if (t < N_SCAN_BLOCKS) partials[t] = (t > 0) ? s[t - 1] : 0;  // exclusive
}

__global__ void dg_scan3(int* __restrict__ offsets, int* __restrict__ cursor,
                         const int* __restrict__ partials) {
    int i = blockIdx.x * SCAN_BLK + threadIdx.x;
    if (i >= N_NODES) return;
    int o = offsets[i] + partials[blockIdx.x];
    offsets[i] = o;
    cursor[i]  = o;
}

// ---------------- Phase 4: compute norm + scatter edges into CSR order ----------------
__global__ void dg_scatter(const int* __restrict__ ei, const float* __restrict__ dis,
                           int* __restrict__ cursor, int* __restrict__ src_sorted,
                           float4* __restrict__ norm_sorted) {
    int e = blockIdx.x * blockDim.x + threadIdx.x;
    if (e >= N_EDGES) return;
    int r = ei[e];
    int c = ei[N_EDGES + e];
    float4 nv;
    nv.x = dis[r * 4 + 0] * dis[c * 4 + 0];
    nv.y = dis[r * 4 + 1] * dis[c * 4 + 1];
    nv.z = dis[r * 4 + 2] * dis[c * 4 + 2];
    nv.w = dis[r * 4 + 3] * dis[c * 4 + 3];
    int pos = atomicAdd(&cursor[c], 1);
    src_sorted[pos]  = r;
    norm_sorted[pos] = nv;
}

// ---------------- Phase 5: aggregation, one wave (64 lanes) per target node ----------------
// MODE 0: layer 1 (Gu/Gi in -> f32 ws); 1: layer 2 (f32 ws -> f32 ws); 2: layer 3 (-> f32 d_out)
template <int MODE>
__global__ void dg_agg(const float* __restrict__ Gu, const float* __restrict__ Gi,
                       const float* __restrict__ xin, float* __restrict__ xout,
                       const int* __restrict__ offsets, const int* __restrict__ counts,
                       const int* __restrict__ src, const float* __restrict__ normf) {
    int wid  = (blockIdx.x * blockDim.x + threadIdx.x) >> 6;  // node id
    int lane = threadIdx.x & 63;
    if (wid >= N_NODES) return;
    int start = offsets[wid];
    int cnt   = counts[wid];
    int k     = lane >> 4;  // intent chunk for this lane
    float acc = 0.f;
    for (int i = 0; i < cnt; ++i) {
        long e = start + i;
        int r = src[e];                       // wave-uniform -> 1 cache line
        float nk = normf[e * 4 + k];          // 4 distinct values per wave
        float xv;
        if (MODE == 0) {
            xv = (r < N_USERS) ? Gu[(long)r * 64 + lane]
                               : Gi[(long)(r - N_USERS) * 64 + lane];
        } else {
            xv = xin[(long)r * 64 + lane];    // 256B coalesced row
        }
        acc = fmaf(nk, xv, acc);
    }
    xout[(long)wid * 64 + lane] = acc;        // f32 write (d_out is float32)
}

extern "C" void kernel_launch(void* const* d_in, const int* in_sizes, int n_in,
                              void* d_out, int out_size, void* d_ws, size_t ws_size,
                              hipStream_t stream) {
    const float* Gu      = (const float*)d_in[0];   // [100000, 64] f32
    const float* Gi      = (const float*)d_in[1];   // [50000, 64]  f32
    const int*   ei      = (const int*)d_in[2];     // [2, 1000000] int32
    const float* intents = (const float*)d_in[3];   // [4, 1000000] f32
    float* out = (float*)d_out;                      // [150000, 4, 16] f32

    // ---- workspace layout (~101 MB) ----
    char* ws = (char*)d_ws;
    size_t off = 0;
    float* deg = (float*)(ws + off);        off += (size_t)N_NODES * 4 * sizeof(float);  // becomes dis
    int* counts = (int*)(ws + off);         off += (size_t)N_NODES * sizeof(int);
    int* offsets = (int*)(ws + off);        off += (size_t)N_NODES * sizeof(int);
    int* cursor = (int*)(ws + off);         off += (size_t)N_NODES * sizeof(int);
    int* partials = (int*)(ws + off);       off += 4096;
    int* src_sorted = (int*)(ws + off);     off += (size_t)N_EDGES * sizeof(int);
    float4* norm_sorted = (float4*)(ws + off); off += (size_t)N_EDGES * sizeof(float4);
    float* bufA = (float*)(ws + off);       off += (size_t)N_NODES * 64 * sizeof(float);
    float* bufB = (float*)(ws + off);       off += (size_t)N_NODES * 64 * sizeof(float);
    (void)ws_size; (void)in_sizes; (void)n_in; (void)out_size;

    hipMemsetAsync(deg, 0, (size_t)N_NODES * 4 * sizeof(float), stream);
    hipMemsetAsync(counts, 0, (size_t)N_NODES * sizeof(int), stream);

    const int BLK = 256;
    int gE = (N_EDGES + BLK - 1) / BLK;

    dg_deg<<<gE, BLK, 0, stream>>>(ei, intents, deg, counts);
    dg_dis<<<(N_NODES * 4 + BLK - 1) / BLK, BLK, 0, stream>>>(deg);
    dg_scan1<<<N_SCAN_BLOCKS, SCAN_BLK, 0, stream>>>(counts, offsets, partials);
    dg_scan2<<<1, 1024, 0, stream>>>(partials);
    dg_scan3<<<N_SCAN_BLOCKS, SCAN_BLK, 0, stream>>>(offsets, cursor, partials);
    dg_scatter<<<gE, BLK, 0, stream>>>(ei, deg, cursor, src_sorted, norm_sorted);

    // aggregation: 4 waves per 256-thread block, one wave per node
    int gN = (N_NODES + 3) / 4;
    const float* normf = (const float*)norm_sorted;
    dg_agg<0><<<gN, BLK, 0, stream>>>(Gu, Gi, nullptr, bufA, offsets, counts, src_sorted, normf);
    dg_agg<1><<<gN, BLK, 0, stream>>>(nullptr, nullptr, bufA, bufB, offsets, counts, src_sorted, normf);
    dg_agg<2><<<gN, BLK, 0, stream>>>(nullptr, nullptr, bufB, out, offsets, counts, src_sorted, normf);
}

// Round 5
// 659.163 us; speedup vs baseline: 1.4270x; 1.4270x over previous
//
#include <hip/hip_runtime.h>
#include <hip/hip_bf16.h>
#include <math.h>

#define N_USERS 100000
#define N_ITEMS 50000
#define N_NODES 150000
#define N_EDGES 1000000
#define N_KEYS  (2 * N_NODES)   // combined histogram: row keys [0,N), col keys [N,2N)
#define SCAN_BLK 512
#define N_SCAN_BLOCKS ((N_KEYS + SCAN_BLK - 1) / SCAN_BLK)  // 586

typedef __hip_bfloat16 bf16;

// col-CSR record: 8 floats (32B) per entry: [0]=src(int) [1]=eid(int) [4..7]=norm(float4)

// ---------- Phase 1: softmax w -> wbuf; combined histogram with returned ranks ----------
__global__ void dg_hist(const int* __restrict__ ei, const float* __restrict__ intents,
                        float4* __restrict__ wbuf, unsigned short* __restrict__ rank_r,
                        unsigned short* __restrict__ rank_c, int* __restrict__ cnt2) {
    int e = blockIdx.x * blockDim.x + threadIdx.x;
    if (e >= N_EDGES) return;
    float v0 = intents[e];
    float v1 = intents[N_EDGES + e];
    float v2 = intents[2 * N_EDGES + e];
    float v3 = intents[3 * N_EDGES + e];
    float m  = fmaxf(fmaxf(v0, v1), fmaxf(v2, v3));
    float e0 = __expf(v0 - m), e1 = __expf(v1 - m), e2 = __expf(v2 - m), e3 = __expf(v3 - m);
    float inv = 1.0f / (e0 + e1 + e2 + e3);
    wbuf[e] = make_float4(e0 * inv, e1 * inv, e2 * inv, e3 * inv);
    int r = ei[e];
    int c = ei[N_EDGES + e];
    rank_r[e] = (unsigned short)atomicAdd(&cnt2[r], 1);
    rank_c[e] = (unsigned short)atomicAdd(&cnt2[N_NODES + c], 1);
}

// ---------- Phase 2: exclusive scan of cnt2 -> offs ----------
__global__ void dg_scan1(const int* __restrict__ cnt2, int* __restrict__ offs,
                         int* __restrict__ partials) {
    __shared__ int s[SCAN_BLK];
    int t = threadIdx.x;
    int i = blockIdx.x * SCAN_BLK + t;
    int v = (i < N_KEYS) ? cnt2[i] : 0;
    s[t] = v;
    __syncthreads();
    for (int off = 1; off < SCAN_BLK; off <<= 1) {
        int a = (t >= off) ? s[t - off] : 0;
        __syncthreads();
        s[t] += a;
        __syncthreads();
    }
    int incl = s[t];
    if (i < N_KEYS) offs[i] = incl - v;
    if (t == SCAN_BLK - 1) partials[blockIdx.x] = incl;
}

__global__ void dg_scan2(int* __restrict__ partials) {
    __shared__ int s[1024];
    int t = threadIdx.x;
    int v = (t < N_SCAN_BLOCKS) ? partials[t] : 0;
    s[t] = v;
    __syncthreads();
    for (int off = 1; off < 1024; off <<= 1) {
        int a = (t >= off) ? s[t - off] : 0;
        __syncthreads();
        s[t] += a;
        __syncthreads();
    }
    if (t < N_SCAN_BLOCKS) partials[t] = (t > 0) ? s[t - 1] : 0;
}

__global__ void dg_scan3(int* __restrict__ offs, const int* __restrict__ partials) {
    int i = blockIdx.x * SCAN_BLK + threadIdx.x;
    if (i >= N_KEYS) return;
    offs[i] += partials[blockIdx.x];
}

// ---------- Phase 3: deterministic scatter (NO atomics) ----------
__global__ void dg_scatter(const int* __restrict__ ei, const unsigned short* __restrict__ rank_r,
                           const unsigned short* __restrict__ rank_c, const int* __restrict__ offs,
                           int* __restrict__ pool_eid, float* __restrict__ rec) {
    int e = blockIdx.x * blockDim.x + threadIdx.x;
    if (e >= N_EDGES) return;
    int r = ei[e];
    int c = ei[N_EDGES + e];
    int pr = offs[r] + rank_r[e];
    pool_eid[pr] = e;
    long pc = (long)(offs[N_NODES + c] - N_EDGES + rank_c[e]);  // col entries occupy [E,2E)
    int* ip = (int*)(rec + pc * 8);
    ip[0] = r;   // src
    ip[1] = e;   // eid
}

// ---------- Phase 4: deg from CSR segments -> dis (no atomics) ----------
__global__ void dg_degdis(const int* __restrict__ cnt2, const int* __restrict__ offs,
                          const int* __restrict__ pool_eid, const float* __restrict__ rec,
                          const float* __restrict__ wbuf, float* __restrict__ dis) {
    int t = blockIdx.x * blockDim.x + threadIdx.x;  // (node, k)
    if (t >= N_NODES * 4) return;
    int n = t >> 2, k = t & 3;
    float d = 0.f;
    int o = offs[n], cnt = cnt2[n];                       // out-edges (row role)
    for (int i = 0; i < cnt; ++i) {
        int eid = pool_eid[o + i];
        d += wbuf[(long)eid * 4 + k];
    }
    o = offs[N_NODES + n]; cnt = cnt2[N_NODES + n];       // in-edges (col role)
    for (int i = 0; i < cnt; ++i) {
        int eid = ((const int*)rec)[(long)(o - N_EDGES + i) * 8 + 1];
        d += wbuf[(long)eid * 4 + k];
    }
    dis[t] = (d > 0.f) ? rsqrtf(fmaxf(d, 1e-12f)) : 0.f;
}

// ---------- Phase 5a: layer 1 — compute norm inline, store to rec; f32 in -> bf16 out ----------
__global__ void dg_agg0(const float* __restrict__ Gu, const float* __restrict__ Gi,
                        const float* __restrict__ dis, const int* __restrict__ cnt2,
                        const int* __restrict__ offs, float* __restrict__ rec,
                        bf16* __restrict__ xout) {
    int wid  = (blockIdx.x * blockDim.x + threadIdx.x) >> 6;  // node
    int lane = threadIdx.x & 63;
    if (wid >= N_NODES) return;
    int k    = lane >> 4;
    int base = offs[N_NODES + wid] - N_EDGES;
    int cnt  = cnt2[N_NODES + wid];
    float dn = dis[wid * 4 + k];                // hoisted: uniform per (wave,k)
    float acc = 0.f;
    for (int i = 0; i < cnt; ++i) {
        long idx = (long)(base + i);
        int src  = ((const int*)rec)[idx * 8];  // wave-uniform broadcast
        float nk = dis[(long)src * 4 + k] * dn;
        if ((lane & 15) == 0) rec[idx * 8 + 4 + k] = nk;  // persist norm for layers 2-3
        float xv = (src < N_USERS) ? Gu[(long)src * 64 + lane]
                                   : Gi[(long)(src - N_USERS) * 64 + lane];
        acc = fmaf(nk, xv, acc);
    }
    xout[(long)wid * 64 + lane] = __float2bfloat16(acc);
}

// ---------- Phase 5b/5c: layers 2,3 — bf16 gather; LAST writes f32 d_out ----------
template <int LAST>
__global__ void dg_aggN(const bf16* __restrict__ xin, bf16* __restrict__ xout_b,
                        float* __restrict__ xout_f, const float* __restrict__ rec,
                        const int* __restrict__ cnt2, const int* __restrict__ offs) {
    int wid  = (blockIdx.x * blockDim.x + threadIdx.x) >> 6;
    int lane = threadIdx.x & 63;
    if (wid >= N_NODES) return;
    int k    = lane >> 4;
    int base = offs[N_NODES + wid] - N_EDGES;
    int cnt  = cnt2[N_NODES + wid];
    float acc = 0.f;
    for (int i = 0; i < cnt; ++i) {
        long idx = (long)(base + i);
        int src  = ((const int*)rec)[idx * 8];
        float nk = rec[idx * 8 + 4 + k];
        float xv = __bfloat162float(xin[(long)src * 64 + lane]);  // 128B coalesced row
        acc = fmaf(nk, xv, acc);
    }
    if (LAST) xout_f[(long)wid * 64 + lane] = acc;
    else      xout_b[(long)wid * 64 + lane] = __float2bfloat16(acc);
}

extern "C" void kernel_launch(void* const* d_in, const int* in_sizes, int n_in,
                              void* d_out, int out_size, void* d_ws, size_t ws_size,
                              hipStream_t stream) {
    const float* Gu      = (const float*)d_in[0];   // [100000, 64] f32
    const float* Gi      = (const float*)d_in[1];   // [50000, 64]  f32
    const int*   ei      = (const int*)d_in[2];     // [2, 1000000] int32
    const float* intents = (const float*)d_in[3];   // [4, 1000000] f32
    float* out = (float*)d_out;                      // [150000, 4, 16] f32

    // ---- workspace layout (~99 MB) ----
    char* ws = (char*)d_ws;
    size_t off = 0;
    float4* wbuf = (float4*)(ws + off);          off += (size_t)N_EDGES * 16;        // 16 MB
    float* rec = (float*)(ws + off);             off += (size_t)N_EDGES * 32;        // 32 MB col-CSR records
    int* pool_eid = (int*)(ws + off);            off += (size_t)N_EDGES * 4;         // 4 MB row-CSR eids
    unsigned short* rank_r = (unsigned short*)(ws + off); off += (size_t)N_EDGES * 2; // 2 MB
    unsigned short* rank_c = (unsigned short*)(ws + off); off += (size_t)N_EDGES * 2; // 2 MB
    int* cnt2 = (int*)(ws + off);                off += (size_t)N_KEYS * 4;          // 1.2 MB
    int* offs = (int*)(ws + off);                off += (size_t)N_KEYS * 4;          // 1.2 MB
    int* partials = (int*)(ws + off);            off += 4096;
    float* dis = (float*)(ws + off);             off += (size_t)N_NODES * 4 * 4;     // 2.4 MB
    bf16* xA = (bf16*)(ws + off);                off += (size_t)N_NODES * 64 * 2;    // 19.2 MB
    bf16* xB = (bf16*)(ws + off);                off += (size_t)N_NODES * 64 * 2;    // 19.2 MB
    (void)ws_size; (void)in_sizes; (void)n_in; (void)out_size;

    hipMemsetAsync(cnt2, 0, (size_t)N_KEYS * sizeof(int), stream);

    const int BLK = 256;
    int gE = (N_EDGES + BLK - 1) / BLK;

    dg_hist<<<gE, BLK, 0, stream>>>(ei, intents, wbuf, rank_r, rank_c, cnt2);
    dg_scan1<<<N_SCAN_BLOCKS, SCAN_BLK, 0, stream>>>(cnt2, offs, partials);
    dg_scan2<<<1, 1024, 0, stream>>>(partials);
    dg_scan3<<<N_SCAN_BLOCKS, SCAN_BLK, 0, stream>>>(offs, partials);
    dg_scatter<<<gE, BLK, 0, stream>>>(ei, rank_r, rank_c, offs, pool_eid, rec);
    dg_degdis<<<(N_NODES * 4 + BLK - 1) / BLK, BLK, 0, stream>>>(cnt2, offs, pool_eid, rec,
                                                                 (const float*)wbuf, dis);

    int gN = (N_NODES * 64 + BLK - 1) / BLK;  // one 64-lane wave per node
    dg_agg0<<<gN, BLK, 0, stream>>>(Gu, Gi, dis, cnt2, offs, rec, xA);
    dg_aggN<0><<<gN, BLK, 0, stream>>>(xA, xB, nullptr, rec, cnt2, offs);
    dg_aggN<1><<<gN, BLK, 0, stream>>>(xB, nullptr, out, rec, cnt2, offs);
}

// Round 6
// 610.763 us; speedup vs baseline: 1.5401x; 1.0792x over previous
//
#include <hip/hip_runtime.h>
#include <hip/hip_bf16.h>
#include <math.h>

#define N_USERS 100000
#define N_ITEMS 50000
#define N_NODES 150000
#define N_EDGES 1000000
#define N_KEYS  (2 * N_NODES)      // row keys [0,N), col keys [N,2N)
#define N_GU_FLAT (N_USERS * 64)   // 6,400,000
#define N_ALL_FLAT (N_NODES * 64)  // 9,600,000
#define SCAN_BLK 512
#define N_SCAN_BLOCKS ((N_KEYS + SCAN_BLK - 1) / SCAN_BLK)

typedef __hip_bfloat16 bf16;
typedef unsigned short ushort_t;

__device__ __forceinline__ ushort_t f2bs(float f) {
    bf16 h = __float2bfloat16(f);
    return *reinterpret_cast<ushort_t*>(&h);
}

// ---------- Phase 1 (fused): softmax w -> wbuf + rank atomics  ||  Gu/Gi -> bf16 xG ----------
__global__ __launch_bounds__(256) void dg_hist_cast(
        const int* __restrict__ ei, const float* __restrict__ intents,
        const float* __restrict__ Gu, const float* __restrict__ Gi, ushort_t* __restrict__ xG,
        float4* __restrict__ wbuf, ushort_t* __restrict__ rank_r, ushort_t* __restrict__ rank_c,
        int* __restrict__ cnt2, int gE) {
    int b = blockIdx.x;
    if (b >= gE) {
        // cast branch: 4 floats per thread, float4 load -> 8B bf16x4 store
        long base = ((long)(b - gE) * 256 + threadIdx.x) * 4;
        if (base >= N_ALL_FLAT) return;
        float4 v = (base < N_GU_FLAT) ? *(const float4*)(Gu + base)
                                      : *(const float4*)(Gi + (base - N_GU_FLAT));
        ushort4 o;
        o.x = f2bs(v.x); o.y = f2bs(v.y); o.z = f2bs(v.z); o.w = f2bs(v.w);
        *(ushort4*)(xG + base) = o;
        return;
    }
    int e = b * 256 + threadIdx.x;
    if (e >= N_EDGES) return;
    float v0 = intents[e];
    float v1 = intents[N_EDGES + e];
    float v2 = intents[2 * N_EDGES + e];
    float v3 = intents[3 * N_EDGES + e];
    float m  = fmaxf(fmaxf(v0, v1), fmaxf(v2, v3));
    float e0 = __expf(v0 - m), e1 = __expf(v1 - m), e2 = __expf(v2 - m), e3 = __expf(v3 - m);
    float inv = 1.0f / (e0 + e1 + e2 + e3);
    wbuf[e] = make_float4(e0 * inv, e1 * inv, e2 * inv, e3 * inv);
    int r = ei[e];
    int c = ei[N_EDGES + e];
    rank_r[e] = (ushort_t)atomicAdd(&cnt2[r], 1);
    rank_c[e] = (ushort_t)atomicAdd(&cnt2[N_NODES + c], 1);
}

// ---------- Phase 2: exclusive scan of cnt2 -> offs ----------
__global__ void dg_scan1(const int* __restrict__ cnt2, int* __restrict__ offs,
                         int* __restrict__ partials) {
    __shared__ int s[SCAN_BLK];
    int t = threadIdx.x;
    int i = blockIdx.x * SCAN_BLK + t;
    int v = (i < N_KEYS) ? cnt2[i] : 0;
    s[t] = v;
    __syncthreads();
    for (int off = 1; off < SCAN_BLK; off <<= 1) {
        int a = (t >= off) ? s[t - off] : 0;
        __syncthreads();
        s[t] += a;
        __syncthreads();
    }
    int incl = s[t];
    if (i < N_KEYS) offs[i] = incl - v;
    if (t == SCAN_BLK - 1) partials[blockIdx.x] = incl;
}

__global__ void dg_scan2(int* __restrict__ partials) {
    __shared__ int s[1024];
    int t = threadIdx.x;
    int v = (t < N_SCAN_BLOCKS) ? partials[t] : 0;
    s[t] = v;
    __syncthreads();
    for (int off = 1; off < 1024; off <<= 1) {
        int a = (t >= off) ? s[t - off] : 0;
        __syncthreads();
        s[t] += a;
        __syncthreads();
    }
    if (t < N_SCAN_BLOCKS) partials[t] = (t > 0) ? s[t - 1] : 0;
}

__global__ void dg_scan3(int* __restrict__ offs, const int* __restrict__ partials) {
    int i = blockIdx.x * SCAN_BLK + threadIdx.x;
    if (i >= N_KEYS) return;
    offs[i] += partials[blockIdx.x];
}

// ---------- Phase 3: deterministic scatter of w into CSR order (no atomics) ----------
__global__ void dg_scatter(const int* __restrict__ ei, const ushort_t* __restrict__ rank_r,
                           const ushort_t* __restrict__ rank_c, const int* __restrict__ offs,
                           const float4* __restrict__ wbuf, float4* __restrict__ row_w,
                           int* __restrict__ col_src, float4* __restrict__ col_nw) {
    int e = blockIdx.x * blockDim.x + threadIdx.x;
    if (e >= N_EDGES) return;
    int r = ei[e];
    int c = ei[N_EDGES + e];
    float4 w = wbuf[e];
    row_w[offs[r] + rank_r[e]] = w;
    int pc = offs[N_NODES + c] - N_EDGES + rank_c[e];  // col entries occupy [E,2E)
    col_src[pc] = r;
    col_nw[pc]  = w;  // holds w for degdis; overwritten with norm by dg_norm
}

// ---------- Phase 4: deg = streaming sum over both CSR segments -> dis ----------
__global__ void dg_degdis(const int* __restrict__ cnt2, const int* __restrict__ offs,
                          const float* __restrict__ row_w, const float* __restrict__ col_w,
                          float* __restrict__ dis) {
    int t = blockIdx.x * blockDim.x + threadIdx.x;  // (node, k)
    if (t >= N_NODES * 4) return;
    int n = t >> 2, k = t & 3;
    float d = 0.f;
    int o = offs[n], c = cnt2[n];
    for (int i = 0; i < c; ++i) d += row_w[(long)(o + i) * 4 + k];
    o = offs[N_NODES + n] - N_EDGES; c = cnt2[N_NODES + n];
    for (int i = 0; i < c; ++i) d += col_w[(long)(o + i) * 4 + k];
    dis[t] = (d > 0.f) ? rsqrtf(fmaxf(d, 1e-12f)) : 0.f;
}

// ---------- Phase 5: norm = dis[src] * dis[dst], overwrites col_nw in place ----------
__global__ __launch_bounds__(256) void dg_norm(const int* __restrict__ cnt2,
                                               const int* __restrict__ offs,
                                               const int* __restrict__ col_src,
                                               float* __restrict__ col_nw,
                                               const float* __restrict__ dis) {
    int wid  = (blockIdx.x * blockDim.x + threadIdx.x) >> 6;  // node
    int lane = threadIdx.x & 63;
    if (wid >= N_NODES) return;
    int base = offs[N_NODES + wid] - N_EDGES;
    int cnt  = cnt2[N_NODES + wid];
    int il = lane >> 2, kk = lane & 3;   // 16 entries x 4 components per iteration
    float dn = dis[wid * 4 + kk];
    for (int i = il; i < cnt; i += 16) {
        long idx = base + i;
        int src  = col_src[idx];
        col_nw[idx * 4 + kk] = dis[(long)src * 4 + kk] * dn;  // 256B coalesced write
    }
}

// ---------- Phase 6: aggregation, one wave per node, bf16 gather ----------
template <int LAST>
__global__ __launch_bounds__(256) void dg_agg(const ushort_t* __restrict__ xin,
                                              ushort_t* __restrict__ xout_b,
                                              float* __restrict__ xout_f,
                                              const int* __restrict__ col_src,
                                              const float* __restrict__ col_nw,
                                              const int* __restrict__ cnt2,
                                              const int* __restrict__ offs) {
    int wid  = (blockIdx.x * blockDim.x + threadIdx.x) >> 6;
    int lane = threadIdx.x & 63;
    if (wid >= N_NODES) return;
    int base = offs[N_NODES + wid] - N_EDGES;
    int cnt  = cnt2[N_NODES + wid];
    int k    = lane >> 4;
    float acc = 0.f;
    for (int i = 0; i < cnt; ++i) {
        long idx = base + i;
        int src  = col_src[idx];              // wave-uniform broadcast (1 line)
        float nk = col_nw[idx * 4 + k];       // one 16B line per wave
        ushort_t u = xin[(long)src * 64 + lane];  // 128B coalesced bf16 row
        float xv;
        *reinterpret_cast<unsigned int*>(&xv) = ((unsigned int)u) << 16;
        acc = fmaf(nk, xv, acc);
    }
    long o = (long)wid * 64 + lane;
    if (LAST) xout_f[o] = acc;
    else      xout_b[o] = f2bs(acc);
}

extern "C" void kernel_launch(void* const* d_in, const int* in_sizes, int n_in,
                              void* d_out, int out_size, void* d_ws, size_t ws_size,
                              hipStream_t stream) {
    const float* Gu      = (const float*)d_in[0];   // [100000, 64] f32
    const float* Gi      = (const float*)d_in[1];   // [50000, 64]  f32
    const int*   ei      = (const int*)d_in[2];     // [2, 1000000] int32
    const float* intents = (const float*)d_in[3];   // [4, 1000000] f32
    float* out = (float*)d_out;                      // [150000, 4, 16] f32

    // ---- workspace layout (~99.4 MB, xA aliases wbuf+row_w head) ----
    char* ws = (char*)d_ws;
    size_t off = 0;
    float4* wbuf = (float4*)(ws + off);              // dead after dg_scatter
    ushort_t* xA = (ushort_t*)(ws + off);            // alias: written in agg layer 1
    off += (size_t)N_EDGES * 16;                     // 16 MB
    float4* row_w = (float4*)(ws + off); off += (size_t)N_EDGES * 16;   // 16 MB (dead after degdis; tail-aliased by xA)
    int* col_src = (int*)(ws + off);     off += (size_t)N_EDGES * 4;    // 4 MB
    float4* col_nw = (float4*)(ws + off); off += (size_t)N_EDGES * 16;  // 16 MB (w, then norm)
    ushort_t* rank_r = (ushort_t*)(ws + off); off += (size_t)N_EDGES * 2;
    ushort_t* rank_c = (ushort_t*)(ws + off); off += (size_t)N_EDGES * 2;
    int* cnt2 = (int*)(ws + off);        off += (size_t)N_KEYS * 4;
    int* offs = (int*)(ws + off);        off += (size_t)N_KEYS * 4;
    int* partials = (int*)(ws + off);    off += 4096;
    float* dis = (float*)(ws + off);     off += (size_t)N_NODES * 4 * 4;
    ushort_t* xG = (ushort_t*)(ws + off); off += (size_t)N_ALL_FLAT * 2;  // 19.2 MB bf16 inputs
    ushort_t* xB = (ushort_t*)(ws + off); off += (size_t)N_ALL_FLAT * 2;  // 19.2 MB
    (void)ws_size; (void)in_sizes; (void)n_in; (void)out_size;

    hipMemsetAsync(cnt2, 0, (size_t)N_KEYS * sizeof(int), stream);

    const int BLK = 256;
    int gE = (N_EDGES + BLK - 1) / BLK;                 // 3907 edge blocks
    int gC = (N_ALL_FLAT / 4 + BLK - 1) / BLK;          // 9375 cast blocks

    dg_hist_cast<<<gE + gC, BLK, 0, stream>>>(ei, intents, Gu, Gi, xG, wbuf,
                                              rank_r, rank_c, cnt2, gE);
    dg_scan1<<<N_SCAN_BLOCKS, SCAN_BLK, 0, stream>>>(cnt2, offs, partials);
    dg_scan2<<<1, 1024, 0, stream>>>(partials);
    dg_scan3<<<N_SCAN_BLOCKS, SCAN_BLK, 0, stream>>>(offs, partials);
    dg_scatter<<<gE, BLK, 0, stream>>>(ei, rank_r, rank_c, offs, wbuf, row_w, col_src, col_nw);
    dg_degdis<<<(N_NODES * 4 + BLK - 1) / BLK, BLK, 0, stream>>>(cnt2, offs,
                                                                 (const float*)row_w,
                                                                 (const float*)col_nw, dis);
    dg_norm<<<(N_NODES * 64 + BLK - 1) / BLK, BLK, 0, stream>>>(cnt2, offs, col_src,
                                                                (float*)col_nw, dis);

    int gN = (N_NODES * 64 + BLK - 1) / BLK;  // one 64-lane wave per node
    dg_agg<0><<<gN, BLK, 0, stream>>>(xG, xA, nullptr, col_src, (const float*)col_nw, cnt2, offs);
    dg_agg<0><<<gN, BLK, 0, stream>>>(xA, xB, nullptr, col_src, (const float*)col_nw, cnt2, offs);
    dg_agg<1><<<gN, BLK, 0, stream>>>(xB, nullptr, out, col_src, (const float*)col_nw, cnt2, offs);
}

// Round 7
// 466.525 us; speedup vs baseline: 2.0163x; 1.3092x over previous
//
#include <hip/hip_runtime.h>
#include <hip/hip_bf16.h>
#include <math.h>

#define N_USERS 100000
#define N_ITEMS 50000
#define N_NODES 150000
#define N_EDGES 1000000
#define N_KEYS  (2 * N_NODES)      // row keys [0,N), col keys [N,2N)
#define N_GU_FLAT (N_USERS * 64)   // 6,400,000
#define N_ALL_FLAT (N_NODES * 64)  // 9,600,000
#define SCAN_BLK 512
#define N_SCAN_BLOCKS ((N_KEYS + SCAN_BLK - 1) / SCAN_BLK)

typedef __hip_bfloat16 bf16;
typedef unsigned short ushort_t;

__device__ __forceinline__ ushort_t f2bs(float f) {
    bf16 h = __float2bfloat16(f);
    return *reinterpret_cast<ushort_t*>(&h);
}
__device__ __forceinline__ float bs2f(ushort_t u) {
    float f;
    *reinterpret_cast<unsigned int*>(&f) = ((unsigned int)u) << 16;
    return f;
}

// ---------- Phase 1 (fused): rank atomics  ||  Gu/Gi -> bf16 xG ----------
__global__ __launch_bounds__(256) void dg_hist_cast(
        const int* __restrict__ ei,
        const float* __restrict__ Gu, const float* __restrict__ Gi, ushort_t* __restrict__ xG,
        ushort_t* __restrict__ rank_r, ushort_t* __restrict__ rank_c,
        int* __restrict__ cnt2, int gE) {
    int b = blockIdx.x;
    if (b >= gE) {
        long base = ((long)(b - gE) * 256 + threadIdx.x) * 4;
        if (base >= N_ALL_FLAT) return;
        float4 v = (base < N_GU_FLAT) ? *(const float4*)(Gu + base)
                                      : *(const float4*)(Gi + (base - N_GU_FLAT));
        ushort4 o;
        o.x = f2bs(v.x); o.y = f2bs(v.y); o.z = f2bs(v.z); o.w = f2bs(v.w);
        *(ushort4*)(xG + base) = o;
        return;
    }
    int e = b * 256 + threadIdx.x;
    if (e >= N_EDGES) return;
    int r = ei[e];
    int c = ei[N_EDGES + e];
    rank_r[e] = (ushort_t)atomicAdd(&cnt2[r], 1);
    rank_c[e] = (ushort_t)atomicAdd(&cnt2[N_NODES + c], 1);
}

// ---------- Phase 2: exclusive scan of cnt2 -> offs ----------
__global__ void dg_scan1(const int* __restrict__ cnt2, int* __restrict__ offs,
                         int* __restrict__ partials) {
    __shared__ int s[SCAN_BLK];
    int t = threadIdx.x;
    int i = blockIdx.x * SCAN_BLK + t;
    int v = (i < N_KEYS) ? cnt2[i] : 0;
    s[t] = v;
    __syncthreads();
    for (int off = 1; off < SCAN_BLK; off <<= 1) {
        int a = (t >= off) ? s[t - off] : 0;
        __syncthreads();
        s[t] += a;
        __syncthreads();
    }
    int incl = s[t];
    if (i < N_KEYS) offs[i] = incl - v;
    if (t == SCAN_BLK - 1) partials[blockIdx.x] = incl;
}

__global__ void dg_scan2(int* __restrict__ partials) {
    __shared__ int s[1024];
    int t = threadIdx.x;
    int v = (t < N_SCAN_BLOCKS) ? partials[t] : 0;
    s[t] = v;
    __syncthreads();
    for (int off = 1; off < 1024; off <<= 1) {
        int a = (t >= off) ? s[t - off] : 0;
        __syncthreads();
        s[t] += a;
        __syncthreads();
    }
    if (t < N_SCAN_BLOCKS) partials[t] = (t > 0) ? s[t - 1] : 0;
}

__global__ void dg_scan3(int* __restrict__ offs, const int* __restrict__ partials) {
    int i = blockIdx.x * SCAN_BLK + threadIdx.x;
    if (i >= N_KEYS) return;
    offs[i] += partials[blockIdx.x];
}

// ---------- Phase 3: deterministic scatter; softmax recomputed here (no atomics) ----------
__global__ __launch_bounds__(256) void dg_scatter(
        const int* __restrict__ ei, const float* __restrict__ intents,
        const ushort_t* __restrict__ rank_r, const ushort_t* __restrict__ rank_c,
        const int* __restrict__ offs, float4* __restrict__ row_w,
        int* __restrict__ col_src, float4* __restrict__ col_nw) {
    int e = blockIdx.x * blockDim.x + threadIdx.x;
    if (e >= N_EDGES) return;
    float v0 = intents[e];
    float v1 = intents[N_EDGES + e];
    float v2 = intents[2 * N_EDGES + e];
    float v3 = intents[3 * N_EDGES + e];
    float m  = fmaxf(fmaxf(v0, v1), fmaxf(v2, v3));
    float e0 = __expf(v0 - m), e1 = __expf(v1 - m), e2 = __expf(v2 - m), e3 = __expf(v3 - m);
    float inv = 1.0f / (e0 + e1 + e2 + e3);
    float4 w = make_float4(e0 * inv, e1 * inv, e2 * inv, e3 * inv);
    int r = ei[e];
    int c = ei[N_EDGES + e];
    row_w[offs[r] + rank_r[e]] = w;
    int pc = offs[N_NODES + c] - N_EDGES + rank_c[e];  // col entries occupy [E,2E)
    col_src[pc] = r;
    col_nw[pc]  = w;   // holds w for degdis; overwritten with norm by dg_norm
}

// ---------- Phase 4: deg = streaming sum over both CSR segments -> dis ----------
__global__ void dg_degdis(const int* __restrict__ cnt2, const int* __restrict__ offs,
                          const float* __restrict__ row_w, const float* __restrict__ col_w,
                          float* __restrict__ dis) {
    int t = blockIdx.x * blockDim.x + threadIdx.x;  // (node, k)
    if (t >= N_NODES * 4) return;
    int n = t >> 2, k = t & 3;
    float d = 0.f;
    int o = offs[n], c = cnt2[n];
    for (int i = 0; i < c; ++i) d += row_w[(long)(o + i) * 4 + k];
    o = offs[N_NODES + n] - N_EDGES; c = cnt2[N_NODES + n];
    for (int i = 0; i < c; ++i) d += col_w[(long)(o + i) * 4 + k];
    dis[t] = (d > 0.f) ? rsqrtf(fmaxf(d, 1e-12f)) : 0.f;
}

// ---------- Phase 5: norm = dis[src] * dis[dst] * w, overwrites col_nw in place ----------
__global__ __launch_bounds__(256) void dg_norm(const int* __restrict__ cnt2,
                                               const int* __restrict__ offs,
                                               const int* __restrict__ col_src,
                                               float* __restrict__ col_nw,
                                               const float* __restrict__ dis) {
    int wid  = (blockIdx.x * blockDim.x + threadIdx.x) >> 6;  // node
    int lane = threadIdx.x & 63;
    if (wid >= N_NODES) return;
    int base = offs[N_NODES + wid] - N_EDGES;
    int cnt  = cnt2[N_NODES + wid];
    int il = lane >> 2, kk = lane & 3;   // 16 entries x 4 components per iteration
    float dn = dis[wid * 4 + kk];
    for (int i = il; i < cnt; i += 16) {
        long idx = base + i;
        int src  = col_src[idx];
        col_nw[idx * 4 + kk] = dis[(long)src * 4 + kk] * dn;  // coalesced 256B write
    }
}

// ---------- Phase 6: aggregation — 4 edges per wave-iteration, ushort4 loads ----------
// lane layout: g = lane>>4 (edge subgroup), j = lane&15 (comps 4j..4j+3), k = j>>2 (intent)
template <int LAST>
__global__ __launch_bounds__(256) void dg_agg(const ushort_t* __restrict__ xin,
                                              ushort_t* __restrict__ xout_b,
                                              float* __restrict__ xout_f,
                                              const int* __restrict__ col_src,
                                              const float* __restrict__ col_nw,
                                              const int* __restrict__ cnt2,
                                              const int* __restrict__ offs) {
    int wid  = (blockIdx.x * blockDim.x + threadIdx.x) >> 6;
    int lane = threadIdx.x & 63;
    if (wid >= N_NODES) return;
    int base = offs[N_NODES + wid] - N_EDGES;
    int cnt  = cnt2[N_NODES + wid];
    int g = lane >> 4, j = lane & 15, k = j >> 2;
    float a0 = 0.f, a1 = 0.f, a2 = 0.f, a3 = 0.f;
    for (int i = 0; i < cnt; i += 4) {
        int ii = i + g;
        bool valid = ii < cnt;
        long idx = base + (valid ? ii : cnt - 1);
        int src  = col_src[idx];                    // 4 distinct per wave
        float nk = valid ? col_nw[idx * 4 + k] : 0.f;  // 64B contiguous per wave
        ushort4 u = *(const ushort4*)(xin + (long)src * 64 + j * 4);  // 512B per wave
        a0 = fmaf(nk, bs2f(u.x), a0);
        a1 = fmaf(nk, bs2f(u.y), a1);
        a2 = fmaf(nk, bs2f(u.z), a2);
        a3 = fmaf(nk, bs2f(u.w), a3);
    }
    // reduce the 4 edge subgroups (lanes j, j+16, j+32, j+48)
    a0 += __shfl_xor(a0, 16); a0 += __shfl_xor(a0, 32);
    a1 += __shfl_xor(a1, 16); a1 += __shfl_xor(a1, 32);
    a2 += __shfl_xor(a2, 16); a2 += __shfl_xor(a2, 32);
    a3 += __shfl_xor(a3, 16); a3 += __shfl_xor(a3, 32);
    if (g == 0) {
        long o = (long)wid * 64 + j * 4;
        if (LAST) {
            *(float4*)(xout_f + o) = make_float4(a0, a1, a2, a3);  // 256B coalesced
        } else {
            ushort4 ob;
            ob.x = f2bs(a0); ob.y = f2bs(a1); ob.z = f2bs(a2); ob.w = f2bs(a3);
            *(ushort4*)(xout_b + o) = ob;                          // 128B coalesced
        }
    }
}

extern "C" void kernel_launch(void* const* d_in, const int* in_sizes, int n_in,
                              void* d_out, int out_size, void* d_ws, size_t ws_size,
                              hipStream_t stream) {
    const float* Gu      = (const float*)d_in[0];   // [100000, 64] f32
    const float* Gi      = (const float*)d_in[1];   // [50000, 64]  f32
    const int*   ei      = (const int*)d_in[2];     // [2, 1000000] int32
    const float* intents = (const float*)d_in[3];   // [4, 1000000] f32
    float* out = (float*)d_out;                      // [150000, 4, 16] f32

    // ---- workspace layout (~83 MB); xA aliases [row_w|rank_r|rank_c] (dead after degdis) ----
    char* ws = (char*)d_ws;
    size_t off = 0;
    float4* row_w = (float4*)(ws + off);             // 16 MB, dead after dg_degdis
    ushort_t* xA = (ushort_t*)(ws + off);            // alias, 19.2 MB
    off += (size_t)N_EDGES * 16;
    ushort_t* rank_r = (ushort_t*)(ws + off); off += (size_t)N_EDGES * 2;  // dead after scatter
    ushort_t* rank_c = (ushort_t*)(ws + off); off += (size_t)N_EDGES * 2;
    int* col_src = (int*)(ws + off);     off += (size_t)N_EDGES * 4;    // 4 MB
    float4* col_nw = (float4*)(ws + off); off += (size_t)N_EDGES * 16;  // 16 MB (w, then norm)
    int* cnt2 = (int*)(ws + off);        off += (size_t)N_KEYS * 4;
    int* offs = (int*)(ws + off);        off += (size_t)N_KEYS * 4;
    int* partials = (int*)(ws + off);    off += 4096;
    float* dis = (float*)(ws + off);     off += (size_t)N_NODES * 4 * 4;
    ushort_t* xG = (ushort_t*)(ws + off); off += (size_t)N_ALL_FLAT * 2;  // 19.2 MB bf16 inputs
    ushort_t* xB = (ushort_t*)(ws + off); off += (size_t)N_ALL_FLAT * 2;  // 19.2 MB
    (void)ws_size; (void)in_sizes; (void)n_in; (void)out_size;

    hipMemsetAsync(cnt2, 0, (size_t)N_KEYS * sizeof(int), stream);

    const int BLK = 256;
    int gE = (N_EDGES + BLK - 1) / BLK;                 // 3907 edge blocks
    int gC = (N_ALL_FLAT / 4 + BLK - 1) / BLK;          // 9375 cast blocks

    dg_hist_cast<<<gE + gC, BLK, 0, stream>>>(ei, Gu, Gi, xG, rank_r, rank_c, cnt2, gE);
    dg_scan1<<<N_SCAN_BLOCKS, SCAN_BLK, 0, stream>>>(cnt2, offs, partials);
    dg_scan2<<<1, 1024, 0, stream>>>(partials);
    dg_scan3<<<N_SCAN_BLOCKS, SCAN_BLK, 0, stream>>>(offs, partials);
    dg_scatter<<<gE, BLK, 0, stream>>>(ei, intents, rank_r, rank_c, offs, row_w, col_src, col_nw);
    dg_degdis<<<(N_NODES * 4 + BLK - 1) / BLK, BLK, 0, stream>>>(cnt2, offs,
                                                                 (const float*)row_w,
                                                                 (const float*)col_nw, dis);
    dg_norm<<<(N_NODES * 64 + BLK - 1) / BLK, BLK, 0, stream>>>(cnt2, offs, col_src,
                                                                (float*)col_nw, dis);

    int gN = (N_NODES * 64 + BLK - 1) / BLK;  // one 64-lane wave per node
    dg_agg<0><<<gN, BLK, 0, stream>>>(xG, xA, nullptr, col_src, (const float*)col_nw, cnt2, offs);
    dg_agg<0><<<gN, BLK, 0, stream>>>(xA, xB, nullptr, col_src, (const float*)col_nw, cnt2, offs);
    dg_agg<1><<<gN, BLK, 0, stream>>>(xB, nullptr, out, col_src, (const float*)col_nw, cnt2, offs);
}

// Round 8
// 431.416 us; speedup vs baseline: 2.1804x; 1.0814x over previous
//
#include <hip/hip_runtime.h>
#include <hip/hip_bf16.h>
#include <math.h>

#define N_USERS 100000
#define N_ITEMS 50000
#define N_NODES 150000
#define N_EDGES 1000000
#define N_KEYS  (2 * N_NODES)      // row keys [0,N), col keys [N,2N)
#define N_GU_FLAT (N_USERS * 64)   // 6,400,000
#define N_ALL_FLAT (N_NODES * 64)  // 9,600,000
#define SCAN_BLK 512
#define N_SCAN_BLOCKS ((N_KEYS + SCAN_BLK - 1) / SCAN_BLK)

typedef __hip_bfloat16 bf16;
typedef unsigned short ushort_t;
typedef unsigned int uint_t;

__device__ __forceinline__ ushort_t f2bs(float f) {
    bf16 h = __float2bfloat16(f);
    return *reinterpret_cast<ushort_t*>(&h);
}
__device__ __forceinline__ float lo2f(uint_t u) {  // low bf16 of a packed pair
    float f; *reinterpret_cast<uint_t*>(&f) = u << 16; return f;
}
__device__ __forceinline__ float hi2f(uint_t u) {  // high bf16 of a packed pair
    float f; *reinterpret_cast<uint_t*>(&f) = u & 0xFFFF0000u; return f;
}
__device__ __forceinline__ uint_t pack2(float a, float b) {
    return (uint_t)f2bs(a) | ((uint_t)f2bs(b) << 16);
}

// edge record (16B): x=src, y=pad, z=bf16{c0,c1}, w=bf16{c2,c3}  (w during degdis, norm after)

// ---------- Phase 1 (fused): rank atomics  ||  Gu/Gi -> bf16 xG ----------
__global__ __launch_bounds__(256) void dg_hist_cast(
        const int* __restrict__ ei,
        const float* __restrict__ Gu, const float* __restrict__ Gi, ushort_t* __restrict__ xG,
        ushort_t* __restrict__ rank_r, ushort_t* __restrict__ rank_c,
        int* __restrict__ cnt2, int gE) {
    int b = blockIdx.x;
    if (b >= gE) {
        long base = ((long)(b - gE) * 256 + threadIdx.x) * 4;
        if (base >= N_ALL_FLAT) return;
        float4 v = (base < N_GU_FLAT) ? *(const float4*)(Gu + base)
                                      : *(const float4*)(Gi + (base - N_GU_FLAT));
        uint2 o;
        o.x = pack2(v.x, v.y);
        o.y = pack2(v.z, v.w);
        *(uint2*)(xG + base) = o;
        return;
    }
    int e = b * 256 + threadIdx.x;
    if (e >= N_EDGES) return;
    int r = ei[e];
    int c = ei[N_EDGES + e];
    rank_r[e] = (ushort_t)atomicAdd(&cnt2[r], 1);
    rank_c[e] = (ushort_t)atomicAdd(&cnt2[N_NODES + c], 1);
}

// ---------- Phase 2: exclusive scan of cnt2 -> offs ----------
__global__ void dg_scan1(const int* __restrict__ cnt2, int* __restrict__ offs,
                         int* __restrict__ partials) {
    __shared__ int s[SCAN_BLK];
    int t = threadIdx.x;
    int i = blockIdx.x * SCAN_BLK + t;
    int v = (i < N_KEYS) ? cnt2[i] : 0;
    s[t] = v;
    __syncthreads();
    for (int off = 1; off < SCAN_BLK; off <<= 1) {
        int a = (t >= off) ? s[t - off] : 0;
        __syncthreads();
        s[t] += a;
        __syncthreads();
    }
    int incl = s[t];
    if (i < N_KEYS) offs[i] = incl - v;
    if (t == SCAN_BLK - 1) partials[blockIdx.x] = incl;
}

__global__ void dg_scan2(int* __restrict__ partials) {
    __shared__ int s[1024];
    int t = threadIdx.x;
    int v = (t < N_SCAN_BLOCKS) ? partials[t] : 0;
    s[t] = v;
    __syncthreads();
    for (int off = 1; off < 1024; off <<= 1) {
        int a = (t >= off) ? s[t - off] : 0;
        __syncthreads();
        s[t] += a;
        __syncthreads();
    }
    if (t < N_SCAN_BLOCKS) partials[t] = (t > 0) ? s[t - 1] : 0;
}

__global__ void dg_scan3(int* __restrict__ offs, const int* __restrict__ partials) {
    int i = blockIdx.x * SCAN_BLK + threadIdx.x;
    if (i >= N_KEYS) return;
    offs[i] += partials[blockIdx.x];
}

// ---------- Phase 3: deterministic scatter; softmax recomputed here (no atomics) ----------
__global__ __launch_bounds__(256) void dg_scatter(
        const int* __restrict__ ei, const float* __restrict__ intents,
        const ushort_t* __restrict__ rank_r, const ushort_t* __restrict__ rank_c,
        const int* __restrict__ offs, uint2* __restrict__ row_w8,
        uint4* __restrict__ rec) {
    int e = blockIdx.x * blockDim.x + threadIdx.x;
    if (e >= N_EDGES) return;
    float v0 = intents[e];
    float v1 = intents[N_EDGES + e];
    float v2 = intents[2 * N_EDGES + e];
    float v3 = intents[3 * N_EDGES + e];
    float m  = fmaxf(fmaxf(v0, v1), fmaxf(v2, v3));
    float e0 = __expf(v0 - m), e1 = __expf(v1 - m), e2 = __expf(v2 - m), e3 = __expf(v3 - m);
    float inv = 1.0f / (e0 + e1 + e2 + e3);
    uint_t wlo = pack2(e0 * inv, e1 * inv);
    uint_t whi = pack2(e2 * inv, e3 * inv);
    int r = ei[e];
    int c = ei[N_EDGES + e];
    uint2 wp; wp.x = wlo; wp.y = whi;
    row_w8[offs[r] + rank_r[e]] = wp;
    int pc = offs[N_NODES + c] - N_EDGES + rank_c[e];  // col entries indexed [0,E)
    uint4 rc; rc.x = (uint_t)r; rc.y = 0u; rc.z = wlo; rc.w = whi;
    rec[pc] = rc;
}

// ---------- Phase 4: deg = streaming bf16 sums over both CSR segments -> dis ----------
__global__ void dg_degdis(const int* __restrict__ cnt2, const int* __restrict__ offs,
                          const uint_t* __restrict__ row_w8, const uint_t* __restrict__ rec_u,
                          float* __restrict__ dis) {
    int t = blockIdx.x * blockDim.x + threadIdx.x;  // (node, k)
    if (t >= N_NODES * 4) return;
    int n = t >> 2, k = t & 3;
    int hw = k >> 1, odd = k & 1;
    float d = 0.f;
    int o = offs[n], c = cnt2[n];
    for (int i = 0; i < c; ++i) {
        uint_t u = row_w8[(long)(o + i) * 2 + hw];
        d += odd ? hi2f(u) : lo2f(u);
    }
    o = offs[N_NODES + n] - N_EDGES; c = cnt2[N_NODES + n];
    for (int i = 0; i < c; ++i) {
        uint_t u = rec_u[(long)(o + i) * 4 + 2 + hw];
        d += odd ? hi2f(u) : lo2f(u);
    }
    dis[t] = (d > 0.f) ? rsqrtf(fmaxf(d, 1e-12f)) : 0.f;
}

// ---------- Phase 5: norm = dis[src]*dis[dst] -> bf16, overwrites rec nw field ----------
__global__ __launch_bounds__(256) void dg_norm(const int* __restrict__ cnt2,
                                               const int* __restrict__ offs,
                                               uint4* __restrict__ rec,
                                               const float* __restrict__ dis) {
    int wid  = (blockIdx.x * blockDim.x + threadIdx.x) >> 6;  // node
    int lane = threadIdx.x & 63;
    if (wid >= N_NODES) return;
    int base = offs[N_NODES + wid] - N_EDGES;
    int cnt  = cnt2[N_NODES + wid];
    int il = lane >> 2, kk = lane & 3;   // 16 edges x 4 components per iteration
    float dn = dis[wid * 4 + kk];
    for (int i = il; i < cnt; i += 16) {
        long idx = base + i;
        int src  = ((const int*)rec)[idx * 4];          // broadcast among 4 lanes
        float nv = dis[(long)src * 4 + kk] * dn;
        ((ushort_t*)rec)[idx * 8 + 4 + kk] = f2bs(nv);  // nw[kk] at byte 8+2*kk
    }
}

// ---------- Phase 6: aggregation — 8 edges/wave-iter, 16B/lane bf16 gather ----------
// lanes: g = lane>>3 (edge subgroup), j = lane&7 (comps 8j..8j+7, intent k = j>>1)
template <int LAST>
__global__ __launch_bounds__(256) void dg_agg(const ushort_t* __restrict__ xin,
                                              ushort_t* __restrict__ xout_b,
                                              float* __restrict__ xout_f,
                                              const uint4* __restrict__ rec,
                                              const int* __restrict__ cnt2,
                                              const int* __restrict__ offs) {
    int wid  = (blockIdx.x * blockDim.x + threadIdx.x) >> 6;
    int lane = threadIdx.x & 63;
    if (wid >= N_NODES) return;
    int base = offs[N_NODES + wid] - N_EDGES;
    int cnt  = cnt2[N_NODES + wid];
    int g = lane >> 3, j = lane & 7, k = j >> 1;
    float a0 = 0.f, a1 = 0.f, a2 = 0.f, a3 = 0.f;
    float a4 = 0.f, a5 = 0.f, a6 = 0.f, a7 = 0.f;
    for (int i = 0; i < cnt; i += 8) {
        int ii = i + g;
        bool valid = ii < cnt;
        long idx = base + (valid ? ii : cnt - 1);
        uint4 rc = rec[idx];                           // 16B broadcast per subgroup
        int src = (int)rc.x;
        uint_t pair = (k < 2) ? rc.z : rc.w;
        float nk = (k & 1) ? hi2f(pair) : lo2f(pair);
        if (!valid) nk = 0.f;
        uint4 xu = *(const uint4*)(xin + (long)src * 64 + j * 8);  // 16B/lane, 1KB/wave
        a0 = fmaf(nk, lo2f(xu.x), a0);
        a1 = fmaf(nk, hi2f(xu.x), a1);
        a2 = fmaf(nk, lo2f(xu.y), a2);
        a3 = fmaf(nk, hi2f(xu.y), a3);
        a4 = fmaf(nk, lo2f(xu.z), a4);
        a5 = fmaf(nk, hi2f(xu.z), a5);
        a6 = fmaf(nk, lo2f(xu.w), a6);
        a7 = fmaf(nk, hi2f(xu.w), a7);
    }
    // reduce the 8 edge subgroups (xor 8,16,32 over lanes)
    a0 += __shfl_xor(a0, 8); a0 += __shfl_xor(a0, 16); a0 += __shfl_xor(a0, 32);
    a1 += __shfl_xor(a1, 8); a1 += __shfl_xor(a1, 16); a1 += __shfl_xor(a1, 32);
    a2 += __shfl_xor(a2, 8); a2 += __shfl_xor(a2, 16); a2 += __shfl_xor(a2, 32);
    a3 += __shfl_xor(a3, 8); a3 += __shfl_xor(a3, 16); a3 += __shfl_xor(a3, 32);
    a4 += __shfl_xor(a4, 8); a4 += __shfl_xor(a4, 16); a4 += __shfl_xor(a4, 32);
    a5 += __shfl_xor(a5, 8); a5 += __shfl_xor(a5, 16); a5 += __shfl_xor(a5, 32);
    a6 += __shfl_xor(a6, 8); a6 += __shfl_xor(a6, 16); a6 += __shfl_xor(a6, 32);
    a7 += __shfl_xor(a7, 8); a7 += __shfl_xor(a7, 16); a7 += __shfl_xor(a7, 32);
    if (g == 0) {
        long o = (long)wid * 64 + j * 8;
        if (LAST) {
            *(float4*)(xout_f + o)     = make_float4(a0, a1, a2, a3);
            *(float4*)(xout_f + o + 4) = make_float4(a4, a5, a6, a7);
        } else {
            uint4 ob;
            ob.x = pack2(a0, a1); ob.y = pack2(a2, a3);
            ob.z = pack2(a4, a5); ob.w = pack2(a6, a7);
            *(uint4*)(xout_b + o) = ob;                // 16B/lane, 128B/node
        }
    }
}

extern "C" void kernel_launch(void* const* d_in, const int* in_sizes, int n_in,
                              void* d_out, int out_size, void* d_ws, size_t ws_size,
                              hipStream_t stream) {
    const float* Gu      = (const float*)d_in[0];   // [100000, 64] f32
    const float* Gi      = (const float*)d_in[1];   // [50000, 64]  f32
    const int*   ei      = (const int*)d_in[2];     // [2, 1000000] int32
    const float* intents = (const float*)d_in[3];   // [4, 1000000] f32
    float* out = (float*)d_out;                      // [150000, 4, 16] f32

    // ---- workspace layout (~91 MB) ----
    char* ws = (char*)d_ws;
    size_t off = 0;
    uint2* row_w8 = (uint2*)(ws + off);  off += (size_t)N_EDGES * 8;    // 8 MB (dead after degdis)
    ushort_t* rank_r = (ushort_t*)(ws + off); off += (size_t)N_EDGES * 2;
    ushort_t* rank_c = (ushort_t*)(ws + off); off += (size_t)N_EDGES * 2;
    uint4* rec = (uint4*)(ws + off);     off += (size_t)N_EDGES * 16;   // 16 MB
    int* cnt2 = (int*)(ws + off);        off += (size_t)N_KEYS * 4;
    int* offs = (int*)(ws + off);        off += (size_t)N_KEYS * 4;
    int* partials = (int*)(ws + off);    off += 4096;
    float* dis = (float*)(ws + off);     off += (size_t)N_NODES * 4 * 4;
    ushort_t* xG = (ushort_t*)(ws + off); off += (size_t)N_ALL_FLAT * 2;  // 19.2 MB
    ushort_t* xA = (ushort_t*)(ws + off); off += (size_t)N_ALL_FLAT * 2;  // 19.2 MB
    ushort_t* xB = (ushort_t*)(ws + off); off += (size_t)N_ALL_FLAT * 2;  // 19.2 MB
    (void)ws_size; (void)in_sizes; (void)n_in; (void)out_size;

    hipMemsetAsync(cnt2, 0, (size_t)N_KEYS * sizeof(int), stream);

    const int BLK = 256;
    int gE = (N_EDGES + BLK - 1) / BLK;                 // 3907 edge blocks
    int gC = (N_ALL_FLAT / 4 + BLK - 1) / BLK;          // 9375 cast blocks

    dg_hist_cast<<<gE + gC, BLK, 0, stream>>>(ei, Gu, Gi, xG, rank_r, rank_c, cnt2, gE);
    dg_scan1<<<N_SCAN_BLOCKS, SCAN_BLK, 0, stream>>>(cnt2, offs, partials);
    dg_scan2<<<1, 1024, 0, stream>>>(partials);
    dg_scan3<<<N_SCAN_BLOCKS, SCAN_BLK, 0, stream>>>(offs, partials);
    dg_scatter<<<gE, BLK, 0, stream>>>(ei, intents, rank_r, rank_c, offs, row_w8, rec);
    dg_degdis<<<(N_NODES * 4 + BLK - 1) / BLK, BLK, 0, stream>>>(
        cnt2, offs, (const uint_t*)row_w8, (const uint_t*)rec, dis);
    dg_norm<<<(N_NODES * 64 + BLK - 1) / BLK, BLK, 0, stream>>>(cnt2, offs, rec, dis);

    int gN = (N_NODES * 64 + BLK - 1) / BLK;  // one 64-lane wave per node
    dg_agg<0><<<gN, BLK, 0, stream>>>(xG, xA, nullptr, rec, cnt2, offs);
    dg_agg<0><<<gN, BLK, 0, stream>>>(xA, xB, nullptr, rec, cnt2, offs);
    dg_agg<1><<<gN, BLK, 0, stream>>>(xB, nullptr, out, rec, cnt2, offs);
}